// Round 8
// baseline (28.378 us; speedup 1.0000x reference)
//
#include <hip/hip_runtime.h>

#define BB 2
#define SDIM 1024
#define DDIM 128
#define K1_ROWS 2

#define F4GET(v,k) ((k)==0?(v).x:((k)==1?(v).y:((k)==2?(v).z:(v).w)))

typedef _Float16 h2v __attribute__((ext_vector_type(2)));
typedef _Float16 h8v __attribute__((ext_vector_type(8)));

__device__ __forceinline__ h2v habs2(h2v t) {
    unsigned u = __builtin_bit_cast(unsigned, t) & 0x7FFF7FFFu;
    return __builtin_bit_cast(h2v, u);
}

__device__ __forceinline__ float hdot2(h2v a, h2v b, float acc) {
#if __has_builtin(__builtin_amdgcn_fdot2)
    return __builtin_amdgcn_fdot2(a, b, acc, false);
#else
    acc = fmaf((float)a.x, (float)b.x, acc);
    return fmaf((float)a.y, (float)b.y, acc);
#endif
}

// Row swizzle: chunk' = ch ^ s(row).  s includes row-bit3 so rows 8/16 apart
// land on different bank-quads (A-reads: 4 rows 16 apart -> 4 distinct banks;
// B-reads: 16 rows 4 apart -> 8 banks x 2 = 2-way, free).
__device__ __forceinline__ int rswz(int row) {
    return (row & 7) ^ ((row >> 3) & 7);
}

// ---------------- Kernel 1: projections + row dot products ----------------
// 1024 blocks x 256 thr (4 waves/SIMD).  2 rows/block; tid>>7 picks W1 half.
__global__ __launch_bounds__(256) void proj_kernel(
    const float* __restrict__ x, const float* __restrict__ W1,
    const float* __restrict__ b1, const float* __restrict__ W2,
    const float* __restrict__ b2,
    ushort* __restrict__ hi16, ushort* __restrict__ hjb16,
    float* __restrict__ si2, float* __restrict__ sj2)
{
    __shared__ float sX[K1_ROWS][DDIM];
    __shared__ float sRed[4][K1_ROWS];
    const int tid  = threadIdx.x;
    const int d    = tid & 127;
    const int half = tid >> 7;
    const int r0   = blockIdx.x * K1_ROWS;

    if (tid < K1_ROWS * DDIM / 4) {
        reinterpret_cast<float4*>(&sX[0][0])[tid] =
            reinterpret_cast<const float4*>(x + (size_t)r0 * DDIM)[tid];
    }
    __syncthreads();

    const float* Wh = W1 + (size_t)half * DDIM * DDIM;

    float acc[K1_ROWS];
    #pragma unroll
    for (int r = 0; r < K1_ROWS; ++r) acc[r] = 0.f;

    #pragma unroll 4
    for (int k = 0; k < DDIM; k += 4) {
        float4 xv[K1_ROWS];
        #pragma unroll
        for (int r = 0; r < K1_ROWS; ++r)
            xv[r] = *reinterpret_cast<const float4*>(&sX[r][k]);
        #pragma unroll
        for (int kk = 0; kk < 4; ++kk) {
            float w = Wh[(size_t)(k + kk) * DDIM + d];
            #pragma unroll
            for (int r = 0; r < K1_ROWS; ++r)
                acc[r] = fmaf(F4GET(xv[r], kk), w, acc[r]);
        }
    }

    if (half) {
        const float bv = b1[d];
        #pragma unroll
        for (int r = 0; r < K1_ROWS; ++r) acc[r] += bv;
    }

    ushort* hout = half ? hjb16 : hi16;
    #pragma unroll
    for (int r = 0; r < K1_ROWS; ++r) {
        _Float16 hv = (_Float16)acc[r];
        hout[(size_t)(r0 + r) * DDIM + d] = __builtin_bit_cast(ushort, hv);
    }

    const float wv = W2[d];
    const int lane = tid & 63;
    const int wave = tid >> 6;
    #pragma unroll
    for (int r = 0; r < K1_ROWS; ++r) {
        float v = acc[r] * wv;
        #pragma unroll
        for (int off = 32; off >= 1; off >>= 1)
            v += __shfl_xor(v, off, 64);
        if (lane == 0) sRed[wave][r] = v;
    }
    __syncthreads();
    if (tid < K1_ROWS) {
        si2[r0 + tid] = 0.5f * (sRed[0][tid] + sRed[1][tid]);
    } else if (tid < 2 * K1_ROWS) {
        int r = tid - K1_ROWS;
        sj2[r0 + r] = 0.5f * (sRed[2][r] + sRed[3][r]) + b2[0];
    }
}

// ---------------- Kernel 2: pairwise edge logits (f16, d-split) -----------
// out[b,i,j] = si2[b,i] + sj2[b,j] + sum_d |hi[b,i,d]+hjb[b,j,d]| * 0.5*w2[d]
// 512 thr: wave-group g=tid>>8 handles d-chunks [8g, 8g+8). Each group runs
// the proven 4x4 inner loop (64x64 tile). Partials combined through LDS
// (aliased onto the dead A-tile). Grid 512 blocks -> 4 waves/SIMD.
__global__ __launch_bounds__(512) void edge_kernel(
    const ushort* __restrict__ hi16, const ushort* __restrict__ hjb16,
    const float* __restrict__ si2, const float* __restrict__ sj2,
    const float* __restrict__ W2, float* __restrict__ out)
{
    __shared__ float4 sTileI[1024];   // 16 KB  A tile (h8v slots) / combine buf
    __shared__ float4 sTileJ[1024];   // 16 KB  B tile
    __shared__ float4 sWf[16];        // 256 B  0.5*w2 as f16
    __shared__ float  sSi[64];
    __shared__ float  sSj[64];

    const int b   = blockIdx.z;
    const int i0  = blockIdx.y * 64;
    const int j0  = blockIdx.x * 64;
    const int tid = threadIdx.x;

    // Stage tiles: 1024 h8v per tile, 512 threads -> 2 iters.
    {
        const h8v* srcI = reinterpret_cast<const h8v*>(hi16  + ((size_t)b * SDIM + i0) * DDIM);
        const h8v* srcJ = reinterpret_cast<const h8v*>(hjb16 + ((size_t)b * SDIM + j0) * DDIM);
        h8v* dI = reinterpret_cast<h8v*>(sTileI);
        h8v* dJ = reinterpret_cast<h8v*>(sTileJ);
        #pragma unroll
        for (int p = 0; p < 2; ++p) {
            int idx = p * 512 + tid;          // 0..1023
            int row = idx >> 4, ch = idx & 15;
            int cs  = ch ^ rswz(row);
            dI[row * 16 + cs] = srcI[idx];
            dJ[row * 16 + cs] = srcJ[idx];
        }
    }
    if (tid < DDIM) {
        _Float16 wv = (_Float16)(0.5f * W2[tid]);
        reinterpret_cast<ushort*>(sWf)[tid] = __builtin_bit_cast(ushort, wv);
    } else if (tid < DDIM + 64) {
        sSi[tid - DDIM] = si2[b * SDIM + i0 + (tid - DDIM)];
    } else if (tid < DDIM + 128) {
        sSj[tid - DDIM - 64] = sj2[b * SDIM + j0 + (tid - DDIM - 64)];
    }
    __syncthreads();

    const int t8 = tid & 255;
    const int g  = tid >> 8;       // d-half: chunks [8g, 8g+8)
    const int tx = t8 & 15;        // j: cols tx*4 .. +3
    const int ty = t8 >> 4;        // i: rows ty*4 .. +3
    const int ri = ty * 4;
    const int cj = tx * 4;

    int swzA[4], swzB[4];
    #pragma unroll
    for (int r = 0; r < 4; ++r) swzA[r] = rswz(ri + r);
    #pragma unroll
    for (int c = 0; c < 4; ++c) swzB[c] = rswz(cj + c);

    float acc[4][4];
    #pragma unroll
    for (int r = 0; r < 4; ++r)
        #pragma unroll
        for (int c = 0; c < 4; ++c) acc[r][c] = 0.f;

    const h8v* sAi = reinterpret_cast<const h8v*>(sTileI);
    const h8v* sBj = reinterpret_cast<const h8v*>(sTileJ);
    const h8v* sWv = reinterpret_cast<const h8v*>(sWf);

    const int ch0 = g * 8;
    #pragma unroll 2
    for (int ch = ch0; ch < ch0 + 8; ++ch) {
        h8v A[4], Bv[4];
        #pragma unroll
        for (int r = 0; r < 4; ++r)
            A[r] = sAi[(ri + r) * 16 + (ch ^ swzA[r])];
        #pragma unroll
        for (int c = 0; c < 4; ++c)
            Bv[c] = sBj[(cj + c) * 16 + (ch ^ swzB[c])];
        const h8v Wv = sWv[ch];    // wave-uniform -> broadcast

        #pragma unroll
        for (int r = 0; r < 4; ++r) {
            const h2v* ap = reinterpret_cast<const h2v*>(&A[r]);
            #pragma unroll
            for (int c = 0; c < 4; ++c) {
                const h2v* bp = reinterpret_cast<const h2v*>(&Bv[c]);
                const h2v* wp = reinterpret_cast<const h2v*>(&Wv);
                float a = acc[r][c];
                #pragma unroll
                for (int k = 0; k < 4; ++k) {
                    h2v t = ap[k] + bp[k];          // v_pk_add_f16
                    a = hdot2(habs2(t), wp[k], a);  // v_and + v_dot2_f32_f16
                }
                acc[r][c] = a;
            }
        }
    }

    // Combine d-halves through LDS (A tile is dead -> reuse as buffer).
    __syncthreads();
    if (g == 1) {
        #pragma unroll
        for (int r = 0; r < 4; ++r)
            sTileI[t8 * 4 + (r ^ (t8 & 3))] =
                make_float4(acc[r][0], acc[r][1], acc[r][2], acc[r][3]);
    }
    __syncthreads();
    if (g == 0) {
        #pragma unroll
        for (int r = 0; r < 4; ++r) {
            const float4 p = sTileI[t8 * 4 + (r ^ (t8 & 3))];
            const float sv = sSi[ri + r];
            float4 o;
            o.x = acc[r][0] + p.x + sv + sSj[cj + 0];
            o.y = acc[r][1] + p.y + sv + sSj[cj + 1];
            o.z = acc[r][2] + p.z + sv + sSj[cj + 2];
            o.w = acc[r][3] + p.w + sv + sSj[cj + 3];
            size_t base = (size_t)b * SDIM * SDIM
                        + (size_t)(i0 + ri + r) * SDIM + j0 + cj;
            *reinterpret_cast<float4*>(out + base) = o;
        }
    }
}

extern "C" void kernel_launch(void* const* d_in, const int* in_sizes, int n_in,
                              void* d_out, int out_size, void* d_ws, size_t ws_size,
                              hipStream_t stream) {
    const float* x  = (const float*)d_in[0];
    const float* W1 = (const float*)d_in[1];
    const float* b1 = (const float*)d_in[2];
    const float* W2 = (const float*)d_in[3];
    const float* b2 = (const float*)d_in[4];
    float* out = (float*)d_out;

    char* ws = (char*)d_ws;
    ushort* hi16  = (ushort*)ws;                                   // B*S*D f16
    ushort* hjb16 = hi16 + (size_t)BB * SDIM * DDIM;               // B*S*D f16
    float*  si2   = (float*)(hjb16 + (size_t)BB * SDIM * DDIM);    // B*S f32
    float*  sj2   = si2 + (size_t)BB * SDIM;                       // B*S f32

    proj_kernel<<<BB * SDIM / K1_ROWS, 256, 0, stream>>>(x, W1, b1, W2, b2, hi16, hjb16, si2, sj2);
    edge_kernel<<<dim3(SDIM / 64, SDIM / 64, BB), 512, 0, stream>>>(hi16, hjb16, si2, sj2, W2, out);
}